// Round 13
// baseline (2847.724 us; speedup 1.0000x reference)
//
#include <hip/hip_runtime.h>
#include <hip/hip_bf16.h>

#define N_TOK 4096
#define CCH   512
// CI = 64, B = 8

using f32x4  = __attribute__((ext_vector_type(4))) float;
using f32x16 = __attribute__((ext_vector_type(16))) float;
using bf16x4 = __attribute__((ext_vector_type(4))) short;
using bf16x8 = __attribute__((ext_vector_type(8))) short;
using u32x4  = __attribute__((ext_vector_type(4))) unsigned int;

__device__ __forceinline__ short f2bf(float f) {
  __hip_bfloat16 h = __float2bfloat16(f);
  return __builtin_bit_cast(short, h);
}

// pack RNE-bf16(exp(a)) | RNE-bf16(exp(b))<<16. __expf only (no inline asm in
// value paths — r4/r6 failures both had opaque-asm value producers).
__device__ __forceinline__ unsigned pkexp(float a, float b) {
  unsigned ua = __builtin_bit_cast(unsigned, __expf(a));
  unsigned ub = __builtin_bit_cast(unsigned, __expf(b));
  ua = ua + 0x7fffu + ((ua >> 16) & 1u);
  ub = ub + 0x7fffu + ((ub >> 16) & 1u);
  return (ua >> 16) | (ub & 0xffff0000u);
}

__device__ __forceinline__ f32x16 mfma32(bf16x8 a, bf16x8 b, f32x16 c) {
  return __builtin_amdgcn_mfma_f32_32x32x16_bf16(a, b, c, 0, 0, 0);
}

__device__ __forceinline__ void gload16(const void* g, void* l) {
  __builtin_amdgcn_global_load_lds(
      (const __attribute__((address_space(1))) void*)g,
      (__attribute__((address_space(3))) void*)l, 16, 0, 0);
}

// ---- LDS tile helper: tiles are (rows x 64 bf16) = 128B rows.
// XOR swizzle on 16B granules: phys_granule = logical_granule ^ (row & 7).
__device__ __forceinline__ void stage_tile(short* lds, const short* src, int src_stride,
                                           int granules, int tid, int nthr) {
  for (int g = tid; g < granules; g += nthr) {
    int r = g >> 3, c16 = g & 7;
    bf16x8 v = *(const bf16x8*)(src + r * src_stride + c16 * 8);
    *(bf16x8*)(lds + r * 64 + ((c16 ^ (r & 7)) * 8)) = v;
  }
}

// ---------------- transpose + weight conversion (merged launch) ----------------
__global__ __launch_bounds__(256) void k_prep(
    const float* __restrict__ x, short* __restrict__ xT,
    const float* __restrict__ wq, const float* __restrict__ wk,
    const float* __restrict__ wv, const float* __restrict__ bq,
    const float* __restrict__ bk, short* __restrict__ wqk_bf,
    short* __restrict__ wv_bf, float* __restrict__ bqk) {
  const int tid = threadIdx.x;
  if (blockIdx.z == 8) {
    int bid = blockIdx.x + blockIdx.y * 64;  // 0..511
    int idx = bid * 256 + tid;
    int stride = 512 * 256;
    const int n1 = 128 * 512, n2 = 512 * 512;
    for (int i = idx; i < n1; i += stride) {
      int d = i >> 9, c = i & 511;
      float v = (d < 64) ? wq[d * 512 + c] : wk[(d - 64) * 512 + c];
      wqk_bf[i] = f2bf(v);
    }
    for (int i = idx; i < n2; i += stride) wv_bf[i] = f2bf(wv[i]);
    if (idx < 128) bqk[idx] = (idx < 64) ? bq[idx] : bk[idx - 64];
    return;
  }
  __shared__ float tile[64][65];
  const int b = blockIdx.z, c0 = blockIdx.y * 64, n0 = blockIdx.x * 64;
  const int q = tid & 15, r0 = tid >> 4;
#pragma unroll
  for (int p = 0; p < 4; ++p) {
    int c = r0 + p * 16;
    f32x4 v = *(const f32x4*)&x[((long)b * CCH + c0 + c) * N_TOK + n0 + q * 4];
    tile[c][q * 4 + 0] = v[0]; tile[c][q * 4 + 1] = v[1];
    tile[c][q * 4 + 2] = v[2]; tile[c][q * 4 + 3] = v[3];
  }
  __syncthreads();
#pragma unroll
  for (int p = 0; p < 4; ++p) {
    int n = r0 + p * 16;
    bf16x4 o;
    o[0] = f2bf(tile[q * 4 + 0][n]); o[1] = f2bf(tile[q * 4 + 1][n]);
    o[2] = f2bf(tile[q * 4 + 2][n]); o[3] = f2bf(tile[q * 4 + 3][n]);
    *(bf16x4*)&xT[((long)b * N_TOK + n0 + n) * CCH + c0 + q * 4] = o;
  }
}

// ---------------- QK GEMM: qkT[b,n,m] = xT[b,n,:].wqk[m,:] + bqk[m] ------------
__global__ __launch_bounds__(512) void k_gemm_qk(
    const short* __restrict__ xT, const short* __restrict__ wqk_bf,
    const float* __restrict__ bqk, short* __restrict__ qkT) {
  __shared__ short An[2][128 * 64];
  __shared__ short Bm[2][128 * 64];
  const int b = blockIdx.z;
  const int n0 = blockIdx.x * 128;
  const int tid = threadIdx.x, lane = tid & 63, w = tid >> 6;
  const int l31 = lane & 31, hi = lane >> 5, x7 = l31 & 7;
  const int nw = w & 3, mw = w >> 2;

  const short* asrc[2];
  const short* bsrc[2];
#pragma unroll
  for (int q = 0; q < 2; ++q) {
    int idx = (w * 2 + q) * 64 + lane;
    int r = idx >> 3, g = idx & 7;
    asrc[q] = xT + ((long long)(b * N_TOK + n0 + r)) * 512 + ((g ^ (r & 7)) * 8);
    bsrc[q] = wqk_bf + (long long)r * 512 + ((g ^ (r & 7)) * 8);
  }
#define STAGEQK(buf, kt)                                           \
  do {                                                             \
    _Pragma("unroll")                                              \
    for (int q = 0; q < 2; ++q) {                                  \
      gload16(asrc[q] + (kt), &An[buf][(w * 2 + q) * 512]);        \
      gload16(bsrc[q] + (kt), &Bm[buf][(w * 2 + q) * 512]);        \
    }                                                              \
  } while (0)

  f32x16 oacc[2] = {};
  STAGEQK(0, 0);
#pragma unroll 1
  for (int t = 0; t < 8; ++t) {
    const int cur = t & 1;
    __syncthreads();
    if (t + 1 < 8) STAGEQK(cur ^ 1, (t + 1) * 64);
#pragma unroll
    for (int ks = 0; ks < 4; ++ks) {
      const int gk = 2 * ks + hi;
      int nrow = nw * 32 + l31;
      bf16x8 anf = *(const bf16x8*)(&An[cur][nrow * 64 + ((gk ^ x7) * 8)]);
#pragma unroll
      for (int mf = 0; mf < 2; ++mf) {
        int mrow = mw * 64 + mf * 32 + l31;
        bf16x8 bmf = *(const bf16x8*)(&Bm[cur][mrow * 64 + ((gk ^ x7) * 8)]);
        oacc[mf] = mfma32(anf, bmf, oacc[mf]);
      }
    }
  }
#undef STAGEQK

#pragma unroll
  for (int mf = 0; mf < 2; ++mf) {
    const int m = mw * 64 + mf * 32 + l31;
    const float bias = bqk[m];
#pragma unroll
    for (int tt = 0; tt < 16; ++tt) {
      int n = n0 + nw * 32 + ((tt & 3) + 8 * (tt >> 2) + 4 * hi);
      qkT[((long long)(b * N_TOK + n)) * 128 + m] = f2bf(oacc[mf][tt] + bias);
    }
  }
}

// ---------------- pass A: Zinv[b,i] = 1 / sum_j exp(e[i,j]) ----------------
__global__ __launch_bounds__(256) void k_passA(const short* __restrict__ qkT,
                                               float* __restrict__ Zinv) {
  __shared__ short ql[128 * 64];
  __shared__ short kl[2][128 * 64];
  __shared__ float zbuf[4][128];
  const int b = blockIdx.y, i0 = blockIdx.x * 128;
  const int tid = threadIdx.x, lane = tid & 63, w = tid >> 6;
  const int l31 = lane & 31, hi = lane >> 5;
  const int x7 = l31 & 7;

  stage_tile(ql, qkT + ((long long)b * N_TOK + i0) * 128, 128, 1024, tid, 256);

  const short* ksrc[4];
#pragma unroll
  for (int q = 0; q < 4; ++q) {
    int idx = (w * 4 + q) * 64 + lane;
    int r = idx >> 3, g = idx & 7;
    ksrc[q] = qkT + ((long long)b * N_TOK + r) * 128 + 64 + ((g ^ (r & 7)) * 8);
  }
#define STAGEK(buf, jt)                                              \
  do {                                                               \
    _Pragma("unroll")                                                \
    for (int q = 0; q < 4; ++q)                                      \
      gload16(ksrc[q] + (long long)(jt) * 128 * 128,                 \
              &kl[buf][(w * 4 + q) * 512]);                          \
  } while (0)

  STAGEK(0, 0);
  __syncthreads();

  bf16x8 qfr[4][4];
#pragma unroll
  for (int f = 0; f < 4; ++f)
#pragma unroll
    for (int ks = 0; ks < 4; ++ks)
      qfr[f][ks] = *(const bf16x8*)(&ql[(f * 32 + l31) * 64 + (((2 * ks + hi) ^ x7) * 8)]);

  float zacc[4] = {0.f, 0.f, 0.f, 0.f};
#pragma unroll 1
  for (int jt = 0; jt < 32; ++jt) {
    const int cur = jt & 1;
    if (jt + 1 < 32) STAGEK(cur ^ 1, jt + 1);
    f32x16 sacc[4] = {};
#pragma unroll
    for (int ks = 0; ks < 4; ++ks) {
      bf16x8 kfr = *(const bf16x8*)(&kl[cur][(w * 32 + l31) * 64 + (((2 * ks + hi) ^ x7) * 8)]);
#pragma unroll
      for (int f = 0; f < 4; ++f) sacc[f] = mfma32(kfr, qfr[f][ks], sacc[f]);
    }
#pragma unroll
    for (int f = 0; f < 4; ++f)
#pragma unroll
      for (int t = 0; t < 16; ++t) zacc[f] += __expf(sacc[f][t]);
    __syncthreads();
  }
#undef STAGEK
#pragma unroll
  for (int f = 0; f < 4; ++f) {
    zacc[f] += __shfl_xor(zacc[f], 32, 64);
    if (hi == 0) zbuf[w][f * 32 + l31] = zacc[f];
  }
  __syncthreads();
  if (tid < 128) {
    float z = zbuf[0][tid] + zbuf[1][tid] + zbuf[2][tid] + zbuf[3][tid];
    Zinv[(long long)b * N_TOK + i0 + tid] = 1.0f / z;
  }
}

// ---------------- V GEMM: v_bf[b,m,n] = (wv[m,:].xT[b,n,:] + bv[m]) * Zinv[b,n]
__global__ __launch_bounds__(512) void k_gemm_v(
    const short* __restrict__ wv_bf, const short* __restrict__ xT,
    const float* __restrict__ bv, const float* __restrict__ Zinv,
    short* __restrict__ v_bf) {
  __shared__ short Ab[2][256 * 64];
  __shared__ short Bb[2][256 * 64];
  const int b = blockIdx.z;
  const int n0 = blockIdx.x * 256, m0 = blockIdx.y * 256;
  const int tid = threadIdx.x;
  const int lane = tid & 63, w = tid >> 6;
  const int l31 = lane & 31, hi = lane >> 5;
  const int x7 = l31 & 7;
  const int mw = w >> 2, nw = w & 3;

  const short* asrc[4];
  const short* bsrc[4];
#pragma unroll
  for (int q = 0; q < 4; ++q) {
    int idx = (w * 4 + q) * 64 + lane;
    int r = idx >> 3, g = idx & 7;
    asrc[q] = wv_bf + (long long)(m0 + r) * 512 + ((g ^ (r & 7)) * 8);
    bsrc[q] = xT + ((long long)(b * N_TOK + n0 + r)) * 512 + ((g ^ (r & 7)) * 8);
  }
#define STAGEV(buf, kt)                                                   \
  do {                                                                    \
    _Pragma("unroll")                                                     \
    for (int q = 0; q < 4; ++q) {                                         \
      gload16(asrc[q] + (kt), &Ab[buf][(w * 4 + q) * 512]);               \
      gload16(bsrc[q] + (kt), &Bb[buf][(w * 4 + q) * 512]);               \
    }                                                                     \
  } while (0)

  f32x16 oacc[4][2] = {};
  STAGEV(0, 0);
#pragma unroll 1
  for (int t = 0; t < 8; ++t) {
    const int cur = t & 1;
    __syncthreads();
    if (t + 1 < 8) STAGEV(cur ^ 1, (t + 1) * 64);
#pragma unroll
    for (int ks = 0; ks < 4; ++ks) {
      const int gk = 2 * ks + hi;
      bf16x8 afr[4], bfr[2];
#pragma unroll
      for (int mf = 0; mf < 4; ++mf) {
        int row = mw * 128 + mf * 32 + l31;
        afr[mf] = *(const bf16x8*)(&Ab[cur][row * 64 + ((gk ^ x7) * 8)]);
      }
#pragma unroll
      for (int nf = 0; nf < 2; ++nf) {
        int row = nw * 64 + nf * 32 + l31;
        bfr[nf] = *(const bf16x8*)(&Bb[cur][row * 64 + ((gk ^ x7) * 8)]);
      }
#pragma unroll
      for (int mf = 0; mf < 4; ++mf)
#pragma unroll
        for (int nf = 0; nf < 2; ++nf)
          oacc[mf][nf] = mfma32(afr[mf], bfr[nf], oacc[mf][nf]);
    }
  }
#undef STAGEV

#pragma unroll
  for (int nf = 0; nf < 2; ++nf) {
    const int n = n0 + nw * 64 + nf * 32 + l31;
    const float zi = Zinv[(long long)b * N_TOK + n];
#pragma unroll
    for (int mf = 0; mf < 4; ++mf)
#pragma unroll
      for (int tt = 0; tt < 16; ++tt) {
        int m = m0 + mw * 128 + mf * 32 + ((tt & 3) + 8 * (tt >> 2) + 4 * hi);
        float v = (oacc[mf][nf][tt] + bv[m]) * zi;
        v_bf[((long long)(b * CCH + m)) * N_TOK + n] = f2bf(v);
      }
  }
}

// ---------------- pass B: out[b,c,j] = gamma * sum_i Vs[c,i]*exp(e[i,j]) + x
// r13: identical tile/schedule to the r9 optimum, but DOUBLE-buffered staging
// (80 KB LDS) -> exactly 2 blocks/CU co-resident. Unconfounded occupancy test:
// work per output unchanged (r11's confound removed); one block's barrier/vmcnt
// drains overlap the other's compute. Prefetch depth 1 (issued a full step
// ahead, ~7.5K cyc) -> vmcnt(0) drain is cheap. Same 1-barrier/step proof:
// buf overwritten after barrier t was last read in step t-1, retired by then.
__global__ __launch_bounds__(512, 4) void k_passB(
    const short* __restrict__ qkT, const short* __restrict__ v_bf,
    const float* __restrict__ x, const float* __restrict__ gamma_p,
    float* __restrict__ out) {
  __shared__ short ql[2][64 * 64];    // q rows i (64) x d (64)       16 KB
  __shared__ short vl[2][256 * 64];   // Vs rows c (256) x i (64)     64 KB
  const int b = blockIdx.z;
  const int j0 = blockIdx.x * 256;
  const int c0 = blockIdx.y * 256;
  const int tid = threadIdx.x;
  const int lane = tid & 63, w = tid >> 6;
  const int l31 = lane & 31, hi = lane >> 5;
  const int x7 = l31 & 7;
  const float gamma = *gamma_p;

  bf16x8 kf[4];
  {
    const short* kp = qkT + ((long long)b * N_TOK + j0 + w * 32 + l31) * 128 + 64 + hi * 8;
#pragma unroll
    for (int ks = 0; ks < 4; ++ks) kf[ks] = *(const bf16x8*)(kp + ks * 16);
  }

  const int qidx = w * 64 + lane;
  const int qr = qidx >> 3, qg = qidx & 7;
  const short* qsrc0 = qkT + ((long long)b * N_TOK + qr) * 128 + ((qg ^ (qr & 7)) * 8);
  const short* vsrc0[4];
#pragma unroll
  for (int q = 0; q < 4; ++q) {
    int idx = (w * 4 + q) * 64 + lane;
    int r = idx >> 3, g = idx & 7;
    vsrc0[q] = v_bf + ((long long)(b * CCH + c0 + r)) * N_TOK + ((g ^ (r & 7)) * 8);
  }

  f32x16 oacc[8] = {};

#define STAGE(buf, step)                                              \
  do {                                                                \
    gload16(qsrc0 + (long long)(step) * 64 * 128, &ql[buf][w * 512]); \
    _Pragma("unroll")                                                 \
    for (int q = 0; q < 4; ++q)                                       \
      gload16(vsrc0[q] + (step) * 64, &vl[buf][(w * 4 + q) * 512]);   \
  } while (0)

#define STEP(t, BUF)                                                          \
  do {                                                                        \
    asm volatile("s_waitcnt vmcnt(0)" ::: "memory");                          \
    __builtin_amdgcn_s_barrier();                                             \
    asm volatile("" ::: "memory");                                            \
    __builtin_amdgcn_sched_barrier(0);                                        \
    if ((t) + 1 < 64) STAGE((BUF) ^ 1, (t) + 1);                              \
    f32x16 sacc[2] = {};                                                      \
    _Pragma("unroll")                                                         \
    for (int ks = 0; ks < 4; ++ks) {                                          \
      int gq = ks * 2 + hi;                                                   \
      bf16x8 qf0 = *(const bf16x8*)(&ql[BUF][l31 * 64 + ((gq ^ x7) * 8)]);    \
      bf16x8 qf1 = *(const bf16x8*)(&ql[BUF][(32 + l31) * 64 + ((gq ^ x7) * 8)]); \
      sacc[0] = mfma32(qf0, kf[ks], sacc[0]);                                 \
      sacc[1] = mfma32(qf1, kf[ks], sacc[1]);                                 \
    }                                                                         \
    bf16x8 pb[4];                                                             \
    _Pragma("unroll")                                                         \
    for (int ks = 0; ks < 4; ++ks) {                                          \
      const int f = ks >> 1, kb = ks & 1;                                     \
      unsigned A0 = pkexp(sacc[f][8 * kb + 0], sacc[f][8 * kb + 1]);          \
      unsigned A1 = pkexp(sacc[f][8 * kb + 2], sacc[f][8 * kb + 3]);          \
      unsigned B0 = pkexp(sacc[f][8 * kb + 4], sacc[f][8 * kb + 5]);          \
      unsigned B1 = pkexp(sacc[f][8 * kb + 6], sacc[f][8 * kb + 7]);          \
      unsigned s0 = __shfl_xor(hi ? A0 : B0, 32, 64);                         \
      unsigned s1 = __shfl_xor(hi ? A1 : B1, 32, 64);                         \
      u32x4 wd = {hi ? s0 : A0, hi ? s1 : A1, hi ? B0 : s0, hi ? B1 : s1};    \
      pb[ks] = __builtin_bit_cast(bf16x8, wd);                                \
    }                                                                         \
    __builtin_amdgcn_s_setprio(1);                                            \
    _Pragma("unroll")                                                         \
    for (int ks = 0; ks < 4; ++ks) {                                          \
      const int gk = 2 * ks + hi;                                             \
      _Pragma("unroll")                                                       \
      for (int cf = 0; cf < 8; ++cf) {                                        \
        bf16x8 vf = *(const bf16x8*)(&vl[BUF][(cf * 32 + l31) * 64 + ((gk ^ x7) * 8)]); \
        oacc[cf] = mfma32(vf, pb[ks], oacc[cf]);                              \
      }                                                                       \
    }                                                                         \
    __builtin_amdgcn_s_setprio(0);                                            \
  } while (0)

  STAGE(0, 0);

#pragma unroll 1
  for (int t0 = 0; t0 < 64; t0 += 2) {
    STEP(t0 + 0, 0);
    STEP(t0 + 1, 1);
  }
#undef STEP
#undef STAGE

  const float* xb = x + (long long)b * CCH * N_TOK;
  float* ob = out + (long long)b * CCH * N_TOK;
  const int j = j0 + w * 32 + l31;
#pragma unroll
  for (int cf = 0; cf < 8; ++cf)
#pragma unroll
    for (int tt = 0; tt < 16; ++tt) {
      int c = c0 + cf * 32 + ((tt & 3) + 8 * (tt >> 2) + 4 * hi);
      long long idx = (long long)c * N_TOK + j;
      ob[idx] = gamma * oacc[cf][tt] + xb[idx];
    }
}

extern "C" void kernel_launch(void* const* d_in, const int* in_sizes, int n_in,
                              void* d_out, int out_size, void* d_ws, size_t ws_size,
                              hipStream_t stream) {
  const float* x     = (const float*)d_in[0];
  const float* wq    = (const float*)d_in[1];
  const float* bq    = (const float*)d_in[2];
  const float* wk    = (const float*)d_in[3];
  const float* bk    = (const float*)d_in[4];
  const float* wv    = (const float*)d_in[5];
  const float* bv    = (const float*)d_in[6];
  const float* gamma = (const float*)d_in[7];
  float* out = (float*)d_out;
  char* ws = (char*)d_ws;

  // workspace layout (bytes)
  short* xT     = (short*)(ws);                 // 8*4096*512*2  = 33554432
  short* qkT    = (short*)(ws + 33554432);      // 8*4096*128*2  =  8388608
  short* v_bf   = (short*)(ws + 41943040);      // 8*512*4096*2  = 33554432
  float* Zinv   = (float*)(ws + 75497472);      // 8*4096*4      =   131072
  short* wqk_bf = (short*)(ws + 75628544);      // 128*512*2     =   131072
  short* wv_bf  = (short*)(ws + 75759616);      // 512*512*2     =   524288
  float* bqk    = (float*)(ws + 76283904);      // 128*4         =      512

  k_prep<<<dim3(64, 8, 9), dim3(256), 0, stream>>>(
      x, xT, wq, wk, wv, bq, bk, wqk_bf, wv_bf, bqk);
  k_gemm_qk<<<dim3(32, 1, 8), dim3(512), 0, stream>>>(xT, wqk_bf, bqk, qkT);
  k_passA<<<dim3(32, 8), dim3(256), 0, stream>>>(qkT, Zinv);
  k_gemm_v<<<dim3(16, 2, 8), dim3(512), 0, stream>>>(wv_bf, xT, bv, Zinv, v_bf);
  // passB: double-buffered, 80 KB LDS -> 2 blocks/CU
  k_passB<<<dim3(16, 2, 8), dim3(512), 0, stream>>>(qkT, v_bf, x, gamma, out);
}

// Round 14
// 280.811 us; speedup vs baseline: 10.1411x; 10.1411x over previous
//
#include <hip/hip_runtime.h>
#include <hip/hip_bf16.h>

#define N_TOK 4096
#define CCH   512
// CI = 64, B = 8

using f32x4  = __attribute__((ext_vector_type(4))) float;
using f32x16 = __attribute__((ext_vector_type(16))) float;
using bf16x4 = __attribute__((ext_vector_type(4))) short;
using bf16x8 = __attribute__((ext_vector_type(8))) short;
using u32x4  = __attribute__((ext_vector_type(4))) unsigned int;

__device__ __forceinline__ short f2bf(float f) {
  __hip_bfloat16 h = __float2bfloat16(f);
  return __builtin_bit_cast(short, h);
}

// pack RNE-bf16(exp(a)) | RNE-bf16(exp(b))<<16. __expf only (no inline asm in
// value paths — r4/r6 failures both had opaque-asm value producers).
__device__ __forceinline__ unsigned pkexp(float a, float b) {
  unsigned ua = __builtin_bit_cast(unsigned, __expf(a));
  unsigned ub = __builtin_bit_cast(unsigned, __expf(b));
  ua = ua + 0x7fffu + ((ua >> 16) & 1u);
  ub = ub + 0x7fffu + ((ub >> 16) & 1u);
  return (ua >> 16) | (ub & 0xffff0000u);
}

__device__ __forceinline__ f32x16 mfma32(bf16x8 a, bf16x8 b, f32x16 c) {
  return __builtin_amdgcn_mfma_f32_32x32x16_bf16(a, b, c, 0, 0, 0);
}

__device__ __forceinline__ void gload16(const void* g, void* l) {
  __builtin_amdgcn_global_load_lds(
      (const __attribute__((address_space(1))) void*)g,
      (__attribute__((address_space(3))) void*)l, 16, 0, 0);
}

// ---- LDS tile helper: tiles are (rows x 64 bf16) = 128B rows.
// XOR swizzle on 16B granules: phys_granule = logical_granule ^ (row & 7).
__device__ __forceinline__ void stage_tile(short* lds, const short* src, int src_stride,
                                           int granules, int tid, int nthr) {
  for (int g = tid; g < granules; g += nthr) {
    int r = g >> 3, c16 = g & 7;
    bf16x8 v = *(const bf16x8*)(src + r * src_stride + c16 * 8);
    *(bf16x8*)(lds + r * 64 + ((c16 ^ (r & 7)) * 8)) = v;
  }
}

// ---------------- transpose + weight conversion (merged launch) ----------------
__global__ __launch_bounds__(256) void k_prep(
    const float* __restrict__ x, short* __restrict__ xT,
    const float* __restrict__ wq, const float* __restrict__ wk,
    const float* __restrict__ wv, const float* __restrict__ bq,
    const float* __restrict__ bk, short* __restrict__ wqk_bf,
    short* __restrict__ wv_bf, float* __restrict__ bqk) {
  const int tid = threadIdx.x;
  if (blockIdx.z == 8) {
    int bid = blockIdx.x + blockIdx.y * 64;  // 0..511
    int idx = bid * 256 + tid;
    int stride = 512 * 256;
    const int n1 = 128 * 512, n2 = 512 * 512;
    for (int i = idx; i < n1; i += stride) {
      int d = i >> 9, c = i & 511;
      float v = (d < 64) ? wq[d * 512 + c] : wk[(d - 64) * 512 + c];
      wqk_bf[i] = f2bf(v);
    }
    for (int i = idx; i < n2; i += stride) wv_bf[i] = f2bf(wv[i]);
    if (idx < 128) bqk[idx] = (idx < 64) ? bq[idx] : bk[idx - 64];
    return;
  }
  __shared__ float tile[64][65];
  const int b = blockIdx.z, c0 = blockIdx.y * 64, n0 = blockIdx.x * 64;
  const int q = tid & 15, r0 = tid >> 4;
#pragma unroll
  for (int p = 0; p < 4; ++p) {
    int c = r0 + p * 16;
    f32x4 v = *(const f32x4*)&x[((long)b * CCH + c0 + c) * N_TOK + n0 + q * 4];
    tile[c][q * 4 + 0] = v[0]; tile[c][q * 4 + 1] = v[1];
    tile[c][q * 4 + 2] = v[2]; tile[c][q * 4 + 3] = v[3];
  }
  __syncthreads();
#pragma unroll
  for (int p = 0; p < 4; ++p) {
    int n = r0 + p * 16;
    bf16x4 o;
    o[0] = f2bf(tile[q * 4 + 0][n]); o[1] = f2bf(tile[q * 4 + 1][n]);
    o[2] = f2bf(tile[q * 4 + 2][n]); o[3] = f2bf(tile[q * 4 + 3][n]);
    *(bf16x4*)&xT[((long)b * N_TOK + n0 + n) * CCH + c0 + q * 4] = o;
  }
}

// ---------------- QK GEMM: qkT[b,n,m] = xT[b,n,:].wqk[m,:] + bqk[m] ------------
__global__ __launch_bounds__(512) void k_gemm_qk(
    const short* __restrict__ xT, const short* __restrict__ wqk_bf,
    const float* __restrict__ bqk, short* __restrict__ qkT) {
  __shared__ short An[2][128 * 64];
  __shared__ short Bm[2][128 * 64];
  const int b = blockIdx.z;
  const int n0 = blockIdx.x * 128;
  const int tid = threadIdx.x, lane = tid & 63, w = tid >> 6;
  const int l31 = lane & 31, hi = lane >> 5, x7 = l31 & 7;
  const int nw = w & 3, mw = w >> 2;

  const short* asrc[2];
  const short* bsrc[2];
#pragma unroll
  for (int q = 0; q < 2; ++q) {
    int idx = (w * 2 + q) * 64 + lane;
    int r = idx >> 3, g = idx & 7;
    asrc[q] = xT + ((long long)(b * N_TOK + n0 + r)) * 512 + ((g ^ (r & 7)) * 8);
    bsrc[q] = wqk_bf + (long long)r * 512 + ((g ^ (r & 7)) * 8);
  }
#define STAGEQK(buf, kt)                                           \
  do {                                                             \
    _Pragma("unroll")                                              \
    for (int q = 0; q < 2; ++q) {                                  \
      gload16(asrc[q] + (kt), &An[buf][(w * 2 + q) * 512]);        \
      gload16(bsrc[q] + (kt), &Bm[buf][(w * 2 + q) * 512]);        \
    }                                                              \
  } while (0)

  f32x16 oacc[2] = {};
  STAGEQK(0, 0);
#pragma unroll 1
  for (int t = 0; t < 8; ++t) {
    const int cur = t & 1;
    __syncthreads();
    if (t + 1 < 8) STAGEQK(cur ^ 1, (t + 1) * 64);
#pragma unroll
    for (int ks = 0; ks < 4; ++ks) {
      const int gk = 2 * ks + hi;
      int nrow = nw * 32 + l31;
      bf16x8 anf = *(const bf16x8*)(&An[cur][nrow * 64 + ((gk ^ x7) * 8)]);
#pragma unroll
      for (int mf = 0; mf < 2; ++mf) {
        int mrow = mw * 64 + mf * 32 + l31;
        bf16x8 bmf = *(const bf16x8*)(&Bm[cur][mrow * 64 + ((gk ^ x7) * 8)]);
        oacc[mf] = mfma32(anf, bmf, oacc[mf]);
      }
    }
  }
#undef STAGEQK

#pragma unroll
  for (int mf = 0; mf < 2; ++mf) {
    const int m = mw * 64 + mf * 32 + l31;
    const float bias = bqk[m];
#pragma unroll
    for (int tt = 0; tt < 16; ++tt) {
      int n = n0 + nw * 32 + ((tt & 3) + 8 * (tt >> 2) + 4 * hi);
      qkT[((long long)(b * N_TOK + n)) * 128 + m] = f2bf(oacc[mf][tt] + bias);
    }
  }
}

// ---------------- pass A: Zinv[b,i] = 1 / sum_j exp(e[i,j]) ----------------
__global__ __launch_bounds__(256) void k_passA(const short* __restrict__ qkT,
                                               float* __restrict__ Zinv) {
  __shared__ short ql[128 * 64];
  __shared__ short kl[2][128 * 64];
  __shared__ float zbuf[4][128];
  const int b = blockIdx.y, i0 = blockIdx.x * 128;
  const int tid = threadIdx.x, lane = tid & 63, w = tid >> 6;
  const int l31 = lane & 31, hi = lane >> 5;
  const int x7 = l31 & 7;

  stage_tile(ql, qkT + ((long long)b * N_TOK + i0) * 128, 128, 1024, tid, 256);

  const short* ksrc[4];
#pragma unroll
  for (int q = 0; q < 4; ++q) {
    int idx = (w * 4 + q) * 64 + lane;
    int r = idx >> 3, g = idx & 7;
    ksrc[q] = qkT + ((long long)b * N_TOK + r) * 128 + 64 + ((g ^ (r & 7)) * 8);
  }
#define STAGEK(buf, jt)                                              \
  do {                                                               \
    _Pragma("unroll")                                                \
    for (int q = 0; q < 4; ++q)                                      \
      gload16(ksrc[q] + (long long)(jt) * 128 * 128,                 \
              &kl[buf][(w * 4 + q) * 512]);                          \
  } while (0)

  STAGEK(0, 0);
  __syncthreads();

  bf16x8 qfr[4][4];
#pragma unroll
  for (int f = 0; f < 4; ++f)
#pragma unroll
    for (int ks = 0; ks < 4; ++ks)
      qfr[f][ks] = *(const bf16x8*)(&ql[(f * 32 + l31) * 64 + (((2 * ks + hi) ^ x7) * 8)]);

  float zacc[4] = {0.f, 0.f, 0.f, 0.f};
#pragma unroll 1
  for (int jt = 0; jt < 32; ++jt) {
    const int cur = jt & 1;
    if (jt + 1 < 32) STAGEK(cur ^ 1, jt + 1);
    f32x16 sacc[4] = {};
#pragma unroll
    for (int ks = 0; ks < 4; ++ks) {
      bf16x8 kfr = *(const bf16x8*)(&kl[cur][(w * 32 + l31) * 64 + (((2 * ks + hi) ^ x7) * 8)]);
#pragma unroll
      for (int f = 0; f < 4; ++f) sacc[f] = mfma32(kfr, qfr[f][ks], sacc[f]);
    }
#pragma unroll
    for (int f = 0; f < 4; ++f)
#pragma unroll
      for (int t = 0; t < 16; ++t) zacc[f] += __expf(sacc[f][t]);
    __syncthreads();
  }
#undef STAGEK
#pragma unroll
  for (int f = 0; f < 4; ++f) {
    zacc[f] += __shfl_xor(zacc[f], 32, 64);
    if (hi == 0) zbuf[w][f * 32 + l31] = zacc[f];
  }
  __syncthreads();
  if (tid < 128) {
    float z = zbuf[0][tid] + zbuf[1][tid] + zbuf[2][tid] + zbuf[3][tid];
    Zinv[(long long)b * N_TOK + i0 + tid] = 1.0f / z;
  }
}

// ---------------- V GEMM: v_bf[b,m,n] = (wv[m,:].xT[b,n,:] + bv[m]) * Zinv[b,n]
__global__ __launch_bounds__(512) void k_gemm_v(
    const short* __restrict__ wv_bf, const short* __restrict__ xT,
    const float* __restrict__ bv, const float* __restrict__ Zinv,
    short* __restrict__ v_bf) {
  __shared__ short Ab[2][256 * 64];
  __shared__ short Bb[2][256 * 64];
  const int b = blockIdx.z;
  const int n0 = blockIdx.x * 256, m0 = blockIdx.y * 256;
  const int tid = threadIdx.x;
  const int lane = tid & 63, w = tid >> 6;
  const int l31 = lane & 31, hi = lane >> 5;
  const int x7 = l31 & 7;
  const int mw = w >> 2, nw = w & 3;

  const short* asrc[4];
  const short* bsrc[4];
#pragma unroll
  for (int q = 0; q < 4; ++q) {
    int idx = (w * 4 + q) * 64 + lane;
    int r = idx >> 3, g = idx & 7;
    asrc[q] = wv_bf + (long long)(m0 + r) * 512 + ((g ^ (r & 7)) * 8);
    bsrc[q] = xT + ((long long)(b * N_TOK + n0 + r)) * 512 + ((g ^ (r & 7)) * 8);
  }
#define STAGEV(buf, kt)                                                   \
  do {                                                                    \
    _Pragma("unroll")                                                     \
    for (int q = 0; q < 4; ++q) {                                         \
      gload16(asrc[q] + (kt), &Ab[buf][(w * 4 + q) * 512]);               \
      gload16(bsrc[q] + (kt), &Bb[buf][(w * 4 + q) * 512]);               \
    }                                                                     \
  } while (0)

  f32x16 oacc[4][2] = {};
  STAGEV(0, 0);
#pragma unroll 1
  for (int t = 0; t < 8; ++t) {
    const int cur = t & 1;
    __syncthreads();
    if (t + 1 < 8) STAGEV(cur ^ 1, (t + 1) * 64);
#pragma unroll
    for (int ks = 0; ks < 4; ++ks) {
      const int gk = 2 * ks + hi;
      bf16x8 afr[4], bfr[2];
#pragma unroll
      for (int mf = 0; mf < 4; ++mf) {
        int row = mw * 128 + mf * 32 + l31;
        afr[mf] = *(const bf16x8*)(&Ab[cur][row * 64 + ((gk ^ x7) * 8)]);
      }
#pragma unroll
      for (int nf = 0; nf < 2; ++nf) {
        int row = nw * 64 + nf * 32 + l31;
        bfr[nf] = *(const bf16x8*)(&Bb[cur][row * 64 + ((gk ^ x7) * 8)]);
      }
#pragma unroll
      for (int mf = 0; mf < 4; ++mf)
#pragma unroll
        for (int nf = 0; nf < 2; ++nf)
          oacc[mf][nf] = mfma32(afr[mf], bfr[nf], oacc[mf][nf]);
    }
  }
#undef STAGEV

#pragma unroll
  for (int nf = 0; nf < 2; ++nf) {
    const int n = n0 + nw * 64 + nf * 32 + l31;
    const float zi = Zinv[(long long)b * N_TOK + n];
#pragma unroll
    for (int mf = 0; mf < 4; ++mf)
#pragma unroll
      for (int tt = 0; tt < 16; ++tt) {
        int m = m0 + mw * 128 + mf * 32 + ((tt & 3) + 8 * (tt >> 2) + 4 * hi);
        float v = (oacc[mf][nf][tt] + bv[m]) * zi;
        v_bf[((long long)(b * CCH + m)) * N_TOK + n] = f2bf(v);
      }
  }
}

// ---------------- pass B: out[b,c,j] = gamma * sum_i Vs[c,i]*exp(e[i,j]) + x
// r14: restore the r9/r12 optimum exactly (200.5 µs). r13's launch_bounds(512,4)
// forced a 128-reg cap -> accumulator spilled to scratch -> 14.4 GB HBM traffic.
// Occupancy is register-bound, not LDS-bound: 252-reg wave state -> 2 waves/SIMD
// hard cap -> 1 block/CU. All structural alternatives measured and worse
// (r3 P-via-LDS, r5 split-b64, r10 2cx4j, r11 half-tile, r13 spill).
__global__ __launch_bounds__(512, 2) void k_passB(
    const short* __restrict__ qkT, const short* __restrict__ v_bf,
    const float* __restrict__ x, const float* __restrict__ gamma_p,
    float* __restrict__ out) {
  __shared__ short ql[3][64 * 64];    // q rows i (64) x d (64)       24 KB
  __shared__ short vl[3][256 * 64];   // Vs rows c (256) x i (64)     96 KB
  const int b = blockIdx.z;
  const int j0 = blockIdx.x * 256;
  const int c0 = blockIdx.y * 256;
  const int tid = threadIdx.x;
  const int lane = tid & 63, w = tid >> 6;
  const int l31 = lane & 31, hi = lane >> 5;
  const int x7 = l31 & 7;
  const float gamma = *gamma_p;

  bf16x8 kf[4];
  {
    const short* kp = qkT + ((long long)b * N_TOK + j0 + w * 32 + l31) * 128 + 64 + hi * 8;
#pragma unroll
    for (int ks = 0; ks < 4; ++ks) kf[ks] = *(const bf16x8*)(kp + ks * 16);
  }

  const int qidx = w * 64 + lane;
  const int qr = qidx >> 3, qg = qidx & 7;
  const short* qsrc0 = qkT + ((long long)b * N_TOK + qr) * 128 + ((qg ^ (qr & 7)) * 8);
  const short* vsrc0[4];
#pragma unroll
  for (int q = 0; q < 4; ++q) {
    int idx = (w * 4 + q) * 64 + lane;
    int r = idx >> 3, g = idx & 7;
    vsrc0[q] = v_bf + ((long long)(b * CCH + c0 + r)) * N_TOK + ((g ^ (r & 7)) * 8);
  }

  f32x16 oacc[8] = {};

#define STAGE(buf, step)                                              \
  do {                                                                \
    gload16(qsrc0 + (long long)(step) * 64 * 128, &ql[buf][w * 512]); \
    _Pragma("unroll")                                                 \
    for (int q = 0; q < 4; ++q)                                       \
      gload16(vsrc0[q] + (step) * 64, &vl[buf][(w * 4 + q) * 512]);   \
  } while (0)

#define STEP(t, BUF)                                                          \
  do {                                                                        \
    if ((t) < 62) { asm volatile("s_waitcnt vmcnt(5)" ::: "memory"); }        \
    else          { asm volatile("s_waitcnt vmcnt(0)" ::: "memory"); }        \
    __builtin_amdgcn_s_barrier();                                             \
    asm volatile("" ::: "memory");                                            \
    __builtin_amdgcn_sched_barrier(0);                                        \
    if ((t) < 62) STAGE((BUF + 2) % 3, (t) + 2);                              \
    f32x16 sacc[2] = {};                                                      \
    _Pragma("unroll")                                                         \
    for (int ks = 0; ks < 4; ++ks) {                                          \
      int gq = ks * 2 + hi;                                                   \
      bf16x8 qf0 = *(const bf16x8*)(&ql[BUF][l31 * 64 + ((gq ^ x7) * 8)]);    \
      bf16x8 qf1 = *(const bf16x8*)(&ql[BUF][(32 + l31) * 64 + ((gq ^ x7) * 8)]); \
      sacc[0] = mfma32(qf0, kf[ks], sacc[0]);                                 \
      sacc[1] = mfma32(qf1, kf[ks], sacc[1]);                                 \
    }                                                                         \
    bf16x8 pb[4];                                                             \
    _Pragma("unroll")                                                         \
    for (int ks = 0; ks < 4; ++ks) {                                          \
      const int f = ks >> 1, kb = ks & 1;                                     \
      unsigned A0 = pkexp(sacc[f][8 * kb + 0], sacc[f][8 * kb + 1]);          \
      unsigned A1 = pkexp(sacc[f][8 * kb + 2], sacc[f][8 * kb + 3]);          \
      unsigned B0 = pkexp(sacc[f][8 * kb + 4], sacc[f][8 * kb + 5]);          \
      unsigned B1 = pkexp(sacc[f][8 * kb + 6], sacc[f][8 * kb + 7]);          \
      unsigned s0 = __shfl_xor(hi ? A0 : B0, 32, 64);                         \
      unsigned s1 = __shfl_xor(hi ? A1 : B1, 32, 64);                         \
      u32x4 wd = {hi ? s0 : A0, hi ? s1 : A1, hi ? B0 : s0, hi ? B1 : s1};    \
      pb[ks] = __builtin_bit_cast(bf16x8, wd);                                \
    }                                                                         \
    __builtin_amdgcn_s_setprio(1);                                            \
    _Pragma("unroll")                                                         \
    for (int ks = 0; ks < 4; ++ks) {                                          \
      const int gk = 2 * ks + hi;                                             \
      _Pragma("unroll")                                                       \
      for (int cf = 0; cf < 8; ++cf) {                                        \
        bf16x8 vf = *(const bf16x8*)(&vl[BUF][(cf * 32 + l31) * 64 + ((gk ^ x7) * 8)]); \
        oacc[cf] = mfma32(vf, pb[ks], oacc[cf]);                              \
      }                                                                       \
    }                                                                         \
    __builtin_amdgcn_s_setprio(0);                                            \
  } while (0)

  STAGE(0, 0);
  STAGE(1, 1);

#pragma unroll 1
  for (int t0 = 0; t0 < 63; t0 += 3) {
    STEP(t0 + 0, 0);
    STEP(t0 + 1, 1);
    STEP(t0 + 2, 2);
  }
  STEP(63, 0);
#undef STEP
#undef STAGE

  const float* xb = x + (long long)b * CCH * N_TOK;
  float* ob = out + (long long)b * CCH * N_TOK;
  const int j = j0 + w * 32 + l31;
#pragma unroll
  for (int cf = 0; cf < 8; ++cf)
#pragma unroll
    for (int tt = 0; tt < 16; ++tt) {
      int c = c0 + cf * 32 + ((tt & 3) + 8 * (tt >> 2) + 4 * hi);
      long long idx = (long long)c * N_TOK + j;
      ob[idx] = gamma * oacc[cf][tt] + xb[idx];
    }
}

extern "C" void kernel_launch(void* const* d_in, const int* in_sizes, int n_in,
                              void* d_out, int out_size, void* d_ws, size_t ws_size,
                              hipStream_t stream) {
  const float* x     = (const float*)d_in[0];
  const float* wq    = (const float*)d_in[1];
  const float* bq    = (const float*)d_in[2];
  const float* wk    = (const float*)d_in[3];
  const float* bk    = (const float*)d_in[4];
  const float* wv    = (const float*)d_in[5];
  const float* bv    = (const float*)d_in[6];
  const float* gamma = (const float*)d_in[7];
  float* out = (float*)d_out;
  char* ws = (char*)d_ws;

  // workspace layout (bytes)
  short* xT     = (short*)(ws);                 // 8*4096*512*2  = 33554432
  short* qkT    = (short*)(ws + 33554432);      // 8*4096*128*2  =  8388608
  short* v_bf   = (short*)(ws + 41943040);      // 8*512*4096*2  = 33554432
  float* Zinv   = (float*)(ws + 75497472);      // 8*4096*4      =   131072
  short* wqk_bf = (short*)(ws + 75628544);      // 128*512*2     =   131072
  short* wv_bf  = (short*)(ws + 75759616);      // 512*512*2     =   524288
  float* bqk    = (float*)(ws + 76283904);      // 128*4         =      512

  k_prep<<<dim3(64, 8, 9), dim3(256), 0, stream>>>(
      x, xT, wq, wk, wv, bq, bk, wqk_bf, wv_bf, bqk);
  k_gemm_qk<<<dim3(32, 1, 8), dim3(512), 0, stream>>>(xT, wqk_bf, bqk, qkT);
  k_passA<<<dim3(32, 8), dim3(256), 0, stream>>>(qkT, Zinv);
  k_gemm_v<<<dim3(16, 2, 8), dim3(512), 0, stream>>>(wv_bf, xT, bv, Zinv, v_bf);
  k_passB<<<dim3(16, 2, 8), dim3(512), 0, stream>>>(qkT, v_bf, x, gamma, out);
}